// Round 8
// baseline (704.376 us; speedup 1.0000x reference)
//
#include <hip/hip_runtime.h>
#include <math.h>

#define T_TRI 20000
#define KNN_K 20
#define H     128

// ---------------- workspace layout (bytes) ----------------
#define WS_GEO   0
#define WS_BQ    (1u<<20)
#define WS_NBR   (2u<<20)
#define WS_RS    (4u<<20)          // rs: 512B
#define WS_WT    ((4u<<20)+4096)   // 5 transposed weights, 5*64KB = 320KB
#define WS_X     (5u<<20)
#define WS_Y     (16u<<20)

__device__ __forceinline__ float readlane_f(float v, int l) {
    return __uint_as_float(__builtin_amdgcn_readlane(__float_as_uint(v), l));
}

// ---------------- geometry ----------------
__global__ void geom_kernel(const float* __restrict__ pts, const int* __restrict__ tris,
                            float* __restrict__ geo, float4* __restrict__ bq) {
    int t = blockIdx.x * blockDim.x + threadIdx.x;
    if (t >= T_TRI) return;
    int i0 = tris[3*t], i1 = tris[3*t+1], i2 = tris[3*t+2];
    float ax = pts[3*i0], ay = pts[3*i0+1], az = pts[3*i0+2];
    float bx = pts[3*i1], by = pts[3*i1+1], bz = pts[3*i1+2];
    float cx = pts[3*i2], cy = pts[3*i2+1], cz = pts[3*i2+2];
    float e0x = ax-bx, e0y = ay-by, e0z = az-bz;   // e_ij
    float e1x = ax-cx, e1y = ay-cy, e1z = az-cz;   // e_ik
    float e2x = bx-cx, e2y = by-cy, e2z = bz-cz;   // e_jk
    float mnx = fminf(fminf(e0x,e1x),e2x), mny = fminf(fminf(e0y,e1y),e2y), mnz = fminf(fminf(e0z,e1z),e2z);
    float mxx = fmaxf(fmaxf(e0x,e1x),e2x), mxy = fmaxf(fmaxf(e0y,e1y),e2y), mxz = fmaxf(fmaxf(e0z,e1z),e2z);
    float gx = (ax+bx+cx)*(1.0f/3.0f), gy = (ay+by+cy)*(1.0f/3.0f), gz = (az+bz+cz)*(1.0f/3.0f);
    float sq = (gx*gx + gy*gy) + gz*gz;
    float* g = geo + (size_t)t*12;
    g[0]=mnx; g[1]=mny; g[2]=mnz; g[3]=mxx; g[4]=mxy; g[5]=mxz;
    g[6]=gx;  g[7]=gy;  g[8]=gz;  g[9]=0.f; g[10]=0.f; g[11]=0.f;
    bq[t] = make_float4(gx, gy, gz, sq);
}

// ---------------- knn: 4 waves/block, 2 rows/wave, sorted top-21 ----------------
// Grid 2500 (T/8) vs R7's 1250: 9.8 blocks/CU available against the 8-block
// residency cap -> full occupancy during the bulk (R7 stalled at 4.88/8=47%).
// Candidate iteration order, distance arithmetic (R1/R3/R4-proven order), and
// event-drain order are IDENTICAL to the passing R7 kernel.
#define KTILE 1024
__global__ __launch_bounds__(256) void knn_kernel(const float4* __restrict__ bq, int* __restrict__ nbr) {
    __shared__ float4 tile[KTILE];
    int wave = threadIdx.x >> 6;
    int lane = threadIdx.x & 63;
    int row0 = blockIdx.x * 8 + wave * 2;

    float4 q0 = bq[row0+0], q1 = bq[row0+1];

    float rd0 = INFINITY, rd1 = INFINITY;
    int   ri0 = 0x7FF00000 | lane, ri1 = ri0;     // distinct sentinels
    float th0 = INFINITY, th1 = INFINITY;
    int   mi0 = 0x7FFFFFFF, mi1 = 0x7FFFFFFF;

#define PROC_ROW(R)                                                                  \
    {                                                                                \
        float dot = fmaf(q##R.z, c.z, fmaf(q##R.y, c.y, q##R.x*c.x));                \
        float d = (q##R.w + c.w) - 2.0f*dot;                                         \
        unsigned long long bal = __ballot(d <= th##R);                               \
        while (bal) {                                                                \
            int src = __ffsll(bal) - 1;                                              \
            bal &= bal - 1;                                                          \
            float dc = readlane_f(d, src);                                           \
            int   jc = kbase + src;                                                  \
            if ((dc < th##R) || (dc == th##R && jc < mi##R)) {                       \
                bool less = (rd##R < dc) || (rd##R == dc && ri##R < jc);             \
                int pos = __popcll(__ballot(less) & 0x1FFFFFull);                    \
                float sd = __shfl_up(rd##R, 1);                                      \
                int   si = __shfl_up(ri##R, 1);                                      \
                if (lane < 21) {                                                     \
                    if (lane == pos)      { rd##R = dc; ri##R = jc; }                \
                    else if (lane > pos)  { rd##R = sd; ri##R = si; }                \
                }                                                                    \
                th##R = readlane_f(rd##R, 20);                                       \
                mi##R = __builtin_amdgcn_readlane(ri##R, 20);                        \
            }                                                                        \
        }                                                                            \
    }

    for (int base = 0; base < T_TRI; base += KTILE) {
        int n = min(KTILE, T_TRI - base);
        __syncthreads();
        for (int k = threadIdx.x; k < n; k += 256) tile[k] = bq[base + k];
        for (int k = n + threadIdx.x; k < KTILE; k += 256)
            tile[k] = make_float4(INFINITY, INFINITY, INFINITY, INFINITY);
        __syncthreads();
#pragma unroll 1
        for (int it = 0; it < KTILE/64; ++it) {
            int kbase = base + it*64;
            float4 c = tile[it*64 + lane];
            PROC_ROW(0)
            PROC_ROW(1)
        }
    }
#undef PROC_ROW
    // lane l holds rank-l entry; rank 0 = self, dropped (== reference idx[:,1:])
    if (lane >= 1 && lane < 21) {
        nbr[(row0+0)*KNN_K + lane - 1] = ri0;
        nbr[(row0+1)*KNN_K + lane - 1] = ri1;
    }
}

// ---------------- layer-0 helpers: y0[t][f] = p[t] * rowsum(W1b)[f] ----------------
__global__ void rowsum_kernel(const float* __restrict__ W1, float* __restrict__ rs) {
    int f = threadIdx.x;
    float s = 0.f;
    for (int c = 0; c < H; ++c) s += W1[f*137 + 9 + c];
    rs[f] = s;
}
__global__ void y0_kernel(const float* __restrict__ p, const float* __restrict__ rs, float* __restrict__ Y) {
    int tid = blockIdx.x * blockDim.x + threadIdx.x;   // over T*H
    int t = tid >> 7, f = tid & 127;
    Y[tid] = p[t] * rs[f];
}

// ---------------- weight pre-transpose (once, tiny) ----------------
// WTg[m][c4][f][k] = W_m[f][col0 + 4*c4 + k]  (m*16384 + c4*512 + f*4 + k)
__global__ void wtrans_kernel(const float* __restrict__ W11, const float* __restrict__ W12,
                              const float* __restrict__ W20, const float* __restrict__ W21,
                              const float* __restrict__ W22, float* __restrict__ WTg) {
    int f = threadIdx.x, c = blockIdx.x, m = blockIdx.y;
    const float* W; int stride, col0;
    if      (m == 0) { W = W11; stride = 137; col0 = 9; }
    else if (m == 1) { W = W12; stride = 137; col0 = 9; }
    else if (m == 2) { W = W20; stride = 128; col0 = 0; }
    else if (m == 3) { W = W21; stride = 128; col0 = 0; }
    else             { W = W22; stride = 128; col0 = 0; }
    WTg[m*16384 + (c>>2)*512 + f*4 + (c&3)] = W[f*stride + col0 + c];
}

// ---------------- standalone dense (the W1b mid-layer GEMM): Y = X@W1b^T ----------------
#define DTPB 16
__global__ __launch_bounds__(128) void dense_kernel(const float* __restrict__ A, const float* __restrict__ WTg,
                             float* __restrict__ C) {
    __shared__ float Ar[8][128];
    int f = threadIdx.x;
    int t0 = blockIdx.x * DTPB;
    for (int tt = 0; tt < DTPB; tt += 8) {
        __syncthreads();
#pragma unroll
        for (int j = 0; j < 8; ++j) Ar[j][f] = A[(size_t)(t0+tt+j)*H + f];
        __syncthreads();
        float a0 = 0.f, a1 = 0.f, a2 = 0.f, a3 = 0.f;
        float a4_ = 0.f, a5 = 0.f, a6 = 0.f, a7 = 0.f;
#pragma unroll
        for (int c4 = 0; c4 < 32; ++c4) {
            float4 w = *(const float4*)&WTg[c4*512 + f*4];
#define DROW(J, ACC)                                                        \
            {                                                               \
                float4 v = ((const float4*)Ar[J])[c4];                      \
                ACC = fmaf(w.x, v.x, ACC); ACC = fmaf(w.y, v.y, ACC);       \
                ACC = fmaf(w.z, v.z, ACC); ACC = fmaf(w.w, v.w, ACC);       \
            }
            DROW(0, a0) DROW(1, a1) DROW(2, a2) DROW(3, a3)
            DROW(4, a4_) DROW(5, a5) DROW(6, a6) DROW(7, a7)
#undef DROW
        }
        C[(size_t)(t0+tt+0)*H + f] = a0;
        C[(size_t)(t0+tt+1)*H + f] = a1;
        C[(size_t)(t0+tt+2)*H + f] = a2;
        C[(size_t)(t0+tt+3)*H + f] = a3;
        C[(size_t)(t0+tt+4)*H + f] = a4_;
        C[(size_t)(t0+tt+5)*H + f] = a5;
        C[(size_t)(t0+tt+6)*H + f] = a6;
        C[(size_t)(t0+tt+7)*H + f] = a7;
    }
}

// ---------------- fused layer: edge(S in LDS) -> dense W2 -> X (or sigmoid head) ----------------
// Block = 256 threads = 4 waves owns 16 triangles. Edge phase: wave w computes
// S rows w*4..w*4+3 into LDS (per-f math and accumulation order identical to
// the R7-passing edge_kernel: lane owns f=lane and f=64+lane, W1a in regs).
// Dense phase: f=tid&127, half=tid>>7 owns 8 rows; W2 from pre-transposed WTg
// (c=0..127 ascending, identical to R7 dense). last!=0: fold the 128-wide Wf
// dot + sigmoid in (butterfly within wave, 2-wave LDS combine) and skip X.
__global__ __launch_bounds__(256) void layer_kernel(const float* __restrict__ Y, const float* __restrict__ geo,
                            const int* __restrict__ nbr, const float* __restrict__ W1,
                            const float* __restrict__ b1, const float* __restrict__ WTg,
                            const float* __restrict__ b2, float* __restrict__ X,
                            const float* __restrict__ Wf, const float* __restrict__ bf,
                            float* __restrict__ out, int last) {
    __shared__ float W1aT[9][128];
    __shared__ float Srow[16][128];
    __shared__ float fpart[4][8];
    for (int idx = threadIdx.x; idx < 9*128; idx += 256) {
        int c = idx >> 7, ff = idx & 127;
        W1aT[c][ff] = W1[ff*137 + c];
    }
    __syncthreads();
    int wave = threadIdx.x >> 6, lane = threadIdx.x & 63;
    int tbase = blockIdx.x * 16;
    {
        float wlo[9], whi[9];
#pragma unroll
        for (int c = 0; c < 9; ++c) { wlo[c] = W1aT[c][lane]; whi[c] = W1aT[c][64+lane]; }
        float b1lo = b1[lane], b1hi = b1[64+lane];
        const float4* g4 = (const float4*)geo;
        for (int u = 0; u < 4; ++u) {
            int t = tbase + wave*4 + u;
            float4 s0 = g4[t*3+0], s1 = g4[t*3+1], s2 = g4[t*3+2];
            float ylo = Y[(size_t)t*H+lane], yhi = Y[(size_t)t*H+64+lane];
            float accLo = 0.f, accHi = 0.f;
#pragma unroll
            for (int e = 0; e < KNN_K; ++e) {
                int tg = nbr[t*KNN_K + e];
                float4 t0 = g4[tg*3+0], t1 = g4[tg*3+1], t2 = g4[tg*3+2];
                float r0 = s0.x-t0.x, r1 = s0.y-t0.y, r2 = s0.z-t0.z, r3 = s0.w-t0.w;
                float r4 = s1.x-t1.x, r5 = s1.y-t1.y, r6 = s1.z-t1.z, r7 = s1.w-t1.w;
                float r8 = s2.x-t2.x;
                float gLo = b1lo;
                gLo = fmaf(wlo[0], r0, gLo); gLo = fmaf(wlo[1], r1, gLo); gLo = fmaf(wlo[2], r2, gLo);
                gLo = fmaf(wlo[3], r3, gLo); gLo = fmaf(wlo[4], r4, gLo);
                gLo = fmaf(wlo[5], r5, gLo); gLo = fmaf(wlo[6], r6, gLo);
                gLo = fmaf(wlo[7], r7, gLo); gLo = fmaf(wlo[8], r8, gLo);
                float gHi = b1hi;
                gHi = fmaf(whi[0], r0, gHi); gHi = fmaf(whi[1], r1, gHi); gHi = fmaf(whi[2], r2, gHi);
                gHi = fmaf(whi[3], r3, gHi); gHi = fmaf(whi[4], r4, gHi);
                gHi = fmaf(whi[5], r5, gHi); gHi = fmaf(whi[6], r6, gHi);
                gHi = fmaf(whi[7], r7, gHi); gHi = fmaf(whi[8], r8, gHi);
                accLo += fmaxf(gLo + ylo - Y[(size_t)tg*H + lane], 0.f);
                accHi += fmaxf(gHi + yhi - Y[(size_t)tg*H + 64 + lane], 0.f);
            }
            Srow[wave*4+u][lane]    = accLo;
            Srow[wave*4+u][64+lane] = accHi;
        }
    }
    __syncthreads();
    int f = threadIdx.x & 127, half = threadIdx.x >> 7;
    float base = b2[f] * (float)KNN_K;
    float a0 = base, a1 = base, a2 = base, a3 = base;
    float a4_ = base, a5 = base, a6 = base, a7 = base;
    const int r0_ = half * 8;
#pragma unroll
    for (int c4 = 0; c4 < 32; ++c4) {
        float4 w = *(const float4*)&WTg[c4*512 + f*4];
#define DROW(J, ACC)                                                        \
        {                                                                   \
            float4 v = ((const float4*)Srow[r0_+J])[c4];                    \
            ACC = fmaf(w.x, v.x, ACC); ACC = fmaf(w.y, v.y, ACC);           \
            ACC = fmaf(w.z, v.z, ACC); ACC = fmaf(w.w, v.w, ACC);           \
        }
        DROW(0, a0) DROW(1, a1) DROW(2, a2) DROW(3, a3)
        DROW(4, a4_) DROW(5, a5) DROW(6, a6) DROW(7, a7)
#undef DROW
    }
    if (!last) {
        X[(size_t)(tbase+r0_+0)*H + f] = a0;
        X[(size_t)(tbase+r0_+1)*H + f] = a1;
        X[(size_t)(tbase+r0_+2)*H + f] = a2;
        X[(size_t)(tbase+r0_+3)*H + f] = a3;
        X[(size_t)(tbase+r0_+4)*H + f] = a4_;
        X[(size_t)(tbase+r0_+5)*H + f] = a5;
        X[(size_t)(tbase+r0_+6)*H + f] = a6;
        X[(size_t)(tbase+r0_+7)*H + f] = a7;
    } else {
        float wf = Wf[f];
        float p0 = a0*wf, p1 = a1*wf, p2 = a2*wf, p3 = a3*wf;
        float p4 = a4_*wf, p5 = a5*wf, p6 = a6*wf, p7 = a7*wf;
#pragma unroll
        for (int off = 32; off >= 1; off >>= 1) {
            p0 += __shfl_xor(p0, off); p1 += __shfl_xor(p1, off);
            p2 += __shfl_xor(p2, off); p3 += __shfl_xor(p3, off);
            p4 += __shfl_xor(p4, off); p5 += __shfl_xor(p5, off);
            p6 += __shfl_xor(p6, off); p7 += __shfl_xor(p7, off);
        }
        if (lane == 0) {
            fpart[wave][0] = p0; fpart[wave][1] = p1; fpart[wave][2] = p2; fpart[wave][3] = p3;
            fpart[wave][4] = p4; fpart[wave][5] = p5; fpart[wave][6] = p6; fpart[wave][7] = p7;
        }
        __syncthreads();
        if (threadIdx.x < 16) {
            int h = threadIdx.x >> 3, j = threadIdx.x & 7;
            float z = fpart[2*h][j] + fpart[2*h+1][j] + bf[0];
            out[tbase + h*8 + j] = 1.0f / (1.0f + expf(-z));
        }
    }
}

extern "C" void kernel_launch(void* const* d_in, const int* in_sizes, int n_in,
                              void* d_out, int out_size, void* d_ws, size_t ws_size,
                              hipStream_t stream) {
    (void)in_sizes; (void)n_in; (void)out_size; (void)ws_size;
    const float* pts   = (const float*)d_in[0];
    const int*   tris  = (const int*)d_in[1];
    const float* probs = (const float*)d_in[2];
    const float* W1[3] = {(const float*)d_in[3],  (const float*)d_in[7],  (const float*)d_in[11]};
    const float* b1[3] = {(const float*)d_in[4],  (const float*)d_in[8],  (const float*)d_in[12]};
    const float* W2[3] = {(const float*)d_in[5],  (const float*)d_in[9],  (const float*)d_in[13]};
    const float* b2[3] = {(const float*)d_in[6],  (const float*)d_in[10], (const float*)d_in[14]};
    const float* Wf = (const float*)d_in[15];
    const float* bf = (const float*)d_in[16];
    float* out = (float*)d_out;

    char* ws = (char*)d_ws;
    float*  geo = (float*)(ws + WS_GEO);
    float4* bq  = (float4*)(ws + WS_BQ);
    int*    nbr = (int*)(ws + WS_NBR);
    float*  rs  = (float*)(ws + WS_RS);
    float*  WTg = (float*)(ws + WS_WT);
    float*  X   = (float*)(ws + WS_X);
    float*  Y   = (float*)(ws + WS_Y);

    geom_kernel<<<(T_TRI+255)/256, 256, 0, stream>>>(pts, tris, geo, bq);
    knn_kernel<<<T_TRI/8, 256, 0, stream>>>(bq, nbr);
    rowsum_kernel<<<1, 128, 0, stream>>>(W1[0], rs);
    wtrans_kernel<<<dim3(128,5), 128, 0, stream>>>(W1[1], W1[2], W2[0], W2[1], W2[2], WTg);
    y0_kernel<<<(T_TRI*H)/256, 256, 0, stream>>>(probs, rs, Y);
    for (int l = 0; l < 3; ++l) {
        if (l > 0)
            dense_kernel<<<T_TRI/DTPB, 128, 0, stream>>>(X, WTg + (size_t)(l-1)*16384, Y);
        layer_kernel<<<T_TRI/16, 256, 0, stream>>>(Y, geo, nbr, W1[l], b1[l],
                                                   WTg + (size_t)(2+l)*16384, b2[l], X,
                                                   Wf, bf, out, (l == 2) ? 1 : 0);
    }
}

// Round 9
// 566.417 us; speedup vs baseline: 1.2436x; 1.2436x over previous
//
#include <hip/hip_runtime.h>
#include <math.h>

#define T_TRI 20000
#define KNN_K 20
#define H     128

// ---------------- workspace layout (bytes) ----------------
#define WS_GEO   0
#define WS_BQ    (1u<<20)
#define WS_NBR   (2u<<20)
#define WS_RS    (4u<<20)          // rs: 512B
#define WS_WT    ((4u<<20)+4096)   // 5 transposed weights, 5*64KB = 320KB
#define WS_X     (5u<<20)
#define WS_Y     (16u<<20)
#define WS_S     (27u<<20)

__device__ __forceinline__ float readlane_f(float v, int l) {
    return __uint_as_float(__builtin_amdgcn_readlane(__float_as_uint(v), l));
}

// ---------------- geometry ----------------
__global__ void geom_kernel(const float* __restrict__ pts, const int* __restrict__ tris,
                            float* __restrict__ geo, float4* __restrict__ bq) {
    int t = blockIdx.x * blockDim.x + threadIdx.x;
    if (t >= T_TRI) return;
    int i0 = tris[3*t], i1 = tris[3*t+1], i2 = tris[3*t+2];
    float ax = pts[3*i0], ay = pts[3*i0+1], az = pts[3*i0+2];
    float bx = pts[3*i1], by = pts[3*i1+1], bz = pts[3*i1+2];
    float cx = pts[3*i2], cy = pts[3*i2+1], cz = pts[3*i2+2];
    float e0x = ax-bx, e0y = ay-by, e0z = az-bz;   // e_ij
    float e1x = ax-cx, e1y = ay-cy, e1z = az-cz;   // e_ik
    float e2x = bx-cx, e2y = by-cy, e2z = bz-cz;   // e_jk
    float mnx = fminf(fminf(e0x,e1x),e2x), mny = fminf(fminf(e0y,e1y),e2y), mnz = fminf(fminf(e0z,e1z),e2z);
    float mxx = fmaxf(fmaxf(e0x,e1x),e2x), mxy = fmaxf(fmaxf(e0y,e1y),e2y), mxz = fmaxf(fmaxf(e0z,e1z),e2z);
    float gx = (ax+bx+cx)*(1.0f/3.0f), gy = (ay+by+cy)*(1.0f/3.0f), gz = (az+bz+cz)*(1.0f/3.0f);
    float sq = (gx*gx + gy*gy) + gz*gz;
    float* g = geo + (size_t)t*12;
    g[0]=mnx; g[1]=mny; g[2]=mnz; g[3]=mxx; g[4]=mxy; g[5]=mxz;
    g[6]=gx;  g[7]=gy;  g[8]=gz;  g[9]=0.f; g[10]=0.f; g[11]=0.f;
    bq[t] = make_float4(gx, gy, gz, sq);
}

// ---------------- knn: 1 row/wave, 4 waves/block, sorted top-21 ----------------
// 20000 waves (19.5/SIMD vs 8-resident cap -> ~2.4 full passes, ~5% tail)
// replaces R8's 10000 (9.8/SIMD, big drain tail at Occ 64%). KTILE 512 keeps
// LDS at 8KB so 8 blocks/CU fit. Candidate enumeration order, distance
// arithmetic (R1/R3/R4-proven order), and event-drain logic are IDENTICAL to
// the R6/R7/R8-passing kernels — selected set is order-independent (strict
// lex total order on (d,idx)).
#define KTILE 512
__global__ __launch_bounds__(256) void knn_kernel(const float4* __restrict__ bq, int* __restrict__ nbr) {
    __shared__ float4 tile[KTILE];
    int wave = threadIdx.x >> 6;
    int lane = threadIdx.x & 63;
    int row  = blockIdx.x * 4 + wave;

    float4 q = bq[row];

    float rd = INFINITY;
    int   ri = 0x7FF00000 | lane;     // distinct sentinels
    float th = INFINITY;
    int   mi = 0x7FFFFFFF;

    for (int base = 0; base < T_TRI; base += KTILE) {
        int n = min(KTILE, T_TRI - base);
        __syncthreads();
        for (int k = threadIdx.x; k < n; k += 256) tile[k] = bq[base + k];
        for (int k = n + threadIdx.x; k < KTILE; k += 256)
            tile[k] = make_float4(INFINITY, INFINITY, INFINITY, INFINITY);
        __syncthreads();
#pragma unroll 1
        for (int it = 0; it < KTILE/64; ++it) {
            int kbase = base + it*64;
            float4 c = tile[it*64 + lane];
            float dot = fmaf(q.z, c.z, fmaf(q.y, c.y, q.x*c.x));
            float d = (q.w + c.w) - 2.0f*dot;
            unsigned long long bal = __ballot(d <= th);
            while (bal) {
                int src = __ffsll(bal) - 1;
                bal &= bal - 1;
                float dc = readlane_f(d, src);
                int   jc = kbase + src;
                if ((dc < th) || (dc == th && jc < mi)) {   // strict re-check vs tightened theta
                    bool less = (rd < dc) || (rd == dc && ri < jc);
                    int pos = __popcll(__ballot(less) & 0x1FFFFFull);
                    float sd = __shfl_up(rd, 1);
                    int   si = __shfl_up(ri, 1);
                    if (lane < 21) {
                        if (lane == pos)      { rd = dc; ri = jc; }
                        else if (lane > pos)  { rd = sd; ri = si; }
                    }
                    th = readlane_f(rd, 20);
                    mi = __builtin_amdgcn_readlane(ri, 20);
                }
            }
        }
    }
    // lane l holds rank-l entry; rank 0 = self, dropped (== reference idx[:,1:])
    if (lane >= 1 && lane < 21) nbr[row*KNN_K + lane - 1] = ri;
}

// ---------------- layer-0 helpers: y0[t][f] = p[t] * rowsum(W1b)[f] ----------------
__global__ void rowsum_kernel(const float* __restrict__ W1, float* __restrict__ rs) {
    int f = threadIdx.x;
    float s = 0.f;
    for (int c = 0; c < H; ++c) s += W1[f*137 + 9 + c];
    rs[f] = s;
}
__global__ void y0_kernel(const float* __restrict__ p, const float* __restrict__ rs, float* __restrict__ Y) {
    int tid = blockIdx.x * blockDim.x + threadIdx.x;   // over T*H
    int t = tid >> 7, f = tid & 127;
    Y[tid] = p[t] * rs[f];
}

// ---------------- weight pre-transpose (once, tiny) ----------------
// WTg[m][c4][f][k] = W_m[f][col0 + 4*c4 + k]  (m*16384 + c4*512 + f*4 + k)
__global__ void wtrans_kernel(const float* __restrict__ W11, const float* __restrict__ W12,
                              const float* __restrict__ W20, const float* __restrict__ W21,
                              const float* __restrict__ W22, float* __restrict__ WTg) {
    int f = threadIdx.x, c = blockIdx.x, m = blockIdx.y;
    const float* W; int stride, col0;
    if      (m == 0) { W = W11; stride = 137; col0 = 9; }
    else if (m == 1) { W = W12; stride = 137; col0 = 9; }
    else if (m == 2) { W = W20; stride = 128; col0 = 0; }
    else if (m == 3) { W = W21; stride = 128; col0 = 0; }
    else             { W = W22; stride = 128; col0 = 0; }
    WTg[m*16384 + (c>>2)*512 + f*4 + (c&3)] = W[f*stride + col0 + c];
}

// ---------------- dense: C[t][f] = sum_c A[t][c]*WT[c][f] + bias[f]*bscale ----------------
// (R7-measured structure, reverted from the R8 fusion.) Weights from the
// pre-transposed interleaved WTg: 1 coalesced dwordx4 per c4 (L2-hot).
// LDS = 4KB (Ar only). Per-row accumulation order c=0..127 — numerics fixed.
#define DTPB 16
__global__ __launch_bounds__(128) void dense_kernel(const float* __restrict__ A, const float* __restrict__ WTg,
                             const float* __restrict__ bias, float bscale,
                             float* __restrict__ C) {
    __shared__ float Ar[8][128];
    int f = threadIdx.x;
    float base = bias ? bias[f]*bscale : 0.0f;
    int t0 = blockIdx.x * DTPB;
    for (int tt = 0; tt < DTPB; tt += 8) {
        __syncthreads();
#pragma unroll
        for (int j = 0; j < 8; ++j) Ar[j][f] = A[(size_t)(t0+tt+j)*H + f];
        __syncthreads();
        float a0 = base, a1 = base, a2 = base, a3 = base;
        float a4_ = base, a5 = base, a6 = base, a7 = base;
#pragma unroll
        for (int c4 = 0; c4 < 32; ++c4) {
            float4 w = *(const float4*)&WTg[c4*512 + f*4];
#define DROW(J, ACC)                                                        \
            {                                                               \
                float4 v = ((const float4*)Ar[J])[c4];                      \
                ACC = fmaf(w.x, v.x, ACC); ACC = fmaf(w.y, v.y, ACC);       \
                ACC = fmaf(w.z, v.z, ACC); ACC = fmaf(w.w, v.w, ACC);       \
            }
            DROW(0, a0) DROW(1, a1) DROW(2, a2) DROW(3, a3)
            DROW(4, a4_) DROW(5, a5) DROW(6, a6) DROW(7, a7)
#undef DROW
        }
        C[(size_t)(t0+tt+0)*H + f] = a0;
        C[(size_t)(t0+tt+1)*H + f] = a1;
        C[(size_t)(t0+tt+2)*H + f] = a2;
        C[(size_t)(t0+tt+3)*H + f] = a3;
        C[(size_t)(t0+tt+4)*H + f] = a4_;
        C[(size_t)(t0+tt+5)*H + f] = a5;
        C[(size_t)(t0+tt+6)*H + f] = a6;
        C[(size_t)(t0+tt+7)*H + f] = a7;
    }
}

// ---------------- edge accumulation: S[t] = sum_e relu(y[t]-y[tgt] + W1a*r9 + b1) ----------------
// (R7-measured structure, reverted from the R8 fusion: 5000 blocks x 4 waves
// = 20000 waves keeps the latency-bound Y-gather fully TLP-hidden — the R8
// 16-tri/block fusion cut this to 5000 waves and regressed 150us.)
__global__ __launch_bounds__(256) void edge_kernel(const float* __restrict__ Y, const float* __restrict__ geo,
                            const int* __restrict__ nbr, const float* __restrict__ W1,
                            const float* __restrict__ b1, float* __restrict__ S) {
    __shared__ float W1aT[9][128];
    for (int idx = threadIdx.x; idx < 9*128; idx += 256) {
        int c = idx >> 7, ff = idx & 127;
        W1aT[c][ff] = W1[ff*137 + c];
    }
    __syncthreads();
    int wave = threadIdx.x >> 6, lane = threadIdx.x & 63;
    int t = blockIdx.x * 4 + wave;
    float wlo[9], whi[9];
#pragma unroll
    for (int c = 0; c < 9; ++c) { wlo[c] = W1aT[c][lane]; whi[c] = W1aT[c][64+lane]; }
    const float4* g4 = (const float4*)geo;
    float4 s0 = g4[t*3+0], s1 = g4[t*3+1], s2 = g4[t*3+2];
    float b1lo = b1[lane],            b1hi = b1[64+lane];
    float ylo  = Y[(size_t)t*H+lane], yhi  = Y[(size_t)t*H+64+lane];
    float accLo = 0.f, accHi = 0.f;
#pragma unroll
    for (int e = 0; e < KNN_K; ++e) {
        int tg = nbr[t*KNN_K + e];
        float4 t0 = g4[tg*3+0], t1 = g4[tg*3+1], t2 = g4[tg*3+2];
        float r0 = s0.x-t0.x, r1 = s0.y-t0.y, r2 = s0.z-t0.z, r3 = s0.w-t0.w;
        float r4 = s1.x-t1.x, r5 = s1.y-t1.y, r6 = s1.z-t1.z, r7 = s1.w-t1.w;
        float r8 = s2.x-t2.x;
        float gLo = b1lo;
        gLo = fmaf(wlo[0], r0, gLo); gLo = fmaf(wlo[1], r1, gLo); gLo = fmaf(wlo[2], r2, gLo);
        gLo = fmaf(wlo[3], r3, gLo); gLo = fmaf(wlo[4], r4, gLo);
        gLo = fmaf(wlo[5], r5, gLo); gLo = fmaf(wlo[6], r6, gLo);
        gLo = fmaf(wlo[7], r7, gLo); gLo = fmaf(wlo[8], r8, gLo);
        float gHi = b1hi;
        gHi = fmaf(whi[0], r0, gHi); gHi = fmaf(whi[1], r1, gHi); gHi = fmaf(whi[2], r2, gHi);
        gHi = fmaf(whi[3], r3, gHi); gHi = fmaf(whi[4], r4, gHi);
        gHi = fmaf(whi[5], r5, gHi); gHi = fmaf(whi[6], r6, gHi);
        gHi = fmaf(whi[7], r7, gHi); gHi = fmaf(whi[8], r8, gHi);
        float preLo = gLo + ylo - Y[(size_t)tg*H + lane];
        float preHi = gHi + yhi - Y[(size_t)tg*H + 64 + lane];
        accLo += fmaxf(preLo, 0.f);
        accHi += fmaxf(preHi, 0.f);
    }
    S[(size_t)t*H + lane]      = accLo;
    S[(size_t)t*H + 64 + lane] = accHi;
}

// ---------------- final head ----------------
__global__ void final_kernel(const float* __restrict__ X, const float* __restrict__ Wf,
                             const float* __restrict__ bf, float* __restrict__ out) {
    int t = blockIdx.x, lane = threadIdx.x;   // 64 threads
    float a = X[(size_t)t*H + lane]*Wf[lane] + X[(size_t)t*H + 64 + lane]*Wf[64+lane];
#pragma unroll
    for (int off = 32; off >= 1; off >>= 1) a += __shfl_xor(a, off);
    if (lane == 0) {
        float z = a + bf[0];
        out[t] = 1.0f / (1.0f + expf(-z));
    }
}

extern "C" void kernel_launch(void* const* d_in, const int* in_sizes, int n_in,
                              void* d_out, int out_size, void* d_ws, size_t ws_size,
                              hipStream_t stream) {
    (void)in_sizes; (void)n_in; (void)out_size; (void)ws_size;
    const float* pts   = (const float*)d_in[0];
    const int*   tris  = (const int*)d_in[1];
    const float* probs = (const float*)d_in[2];
    const float* W1[3] = {(const float*)d_in[3],  (const float*)d_in[7],  (const float*)d_in[11]};
    const float* b1[3] = {(const float*)d_in[4],  (const float*)d_in[8],  (const float*)d_in[12]};
    const float* W2[3] = {(const float*)d_in[5],  (const float*)d_in[9],  (const float*)d_in[13]};
    const float* b2[3] = {(const float*)d_in[6],  (const float*)d_in[10], (const float*)d_in[14]};
    const float* Wf = (const float*)d_in[15];
    const float* bf = (const float*)d_in[16];
    float* out = (float*)d_out;

    char* ws = (char*)d_ws;
    float*  geo = (float*)(ws + WS_GEO);
    float4* bq  = (float4*)(ws + WS_BQ);
    int*    nbr = (int*)(ws + WS_NBR);
    float*  rs  = (float*)(ws + WS_RS);
    float*  WTg = (float*)(ws + WS_WT);
    float*  X   = (float*)(ws + WS_X);
    float*  Y   = (float*)(ws + WS_Y);
    float*  S   = (float*)(ws + WS_S);

    geom_kernel<<<(T_TRI+255)/256, 256, 0, stream>>>(pts, tris, geo, bq);
    knn_kernel<<<T_TRI/4, 256, 0, stream>>>(bq, nbr);
    rowsum_kernel<<<1, 128, 0, stream>>>(W1[0], rs);
    wtrans_kernel<<<dim3(128,5), 128, 0, stream>>>(W1[1], W1[2], W2[0], W2[1], W2[2], WTg);
    y0_kernel<<<(T_TRI*H)/256, 256, 0, stream>>>(probs, rs, Y);
    for (int l = 0; l < 3; ++l) {
        if (l > 0)
            dense_kernel<<<T_TRI/DTPB, 128, 0, stream>>>(X, WTg + (size_t)(l-1)*16384, nullptr, 0.f, Y);
        edge_kernel<<<T_TRI/4, 256, 0, stream>>>(Y, geo, nbr, W1[l], b1[l], S);
        dense_kernel<<<T_TRI/DTPB, 128, 0, stream>>>(S, WTg + (size_t)(2+l)*16384, b2[l], (float)KNN_K, X);
    }
    final_kernel<<<T_TRI, 64, 0, stream>>>(X, Wf, bf, out);
}

// Round 10
// 543.938 us; speedup vs baseline: 1.2950x; 1.0413x over previous
//
#include <hip/hip_runtime.h>
#include <math.h>

#define T_TRI 20000
#define KNN_K 20
#define H     128

// ---------------- workspace layout (bytes) ----------------
#define WS_GEO   0
#define WS_BQ    (1u<<20)
#define WS_NBR   (2u<<20)
#define WS_RS    (4u<<20)          // rs: 512B
#define WS_WT    ((4u<<20)+4096)   // 5 transposed weights, 5*64KB = 320KB
#define WS_X     (5u<<20)
#define WS_Y     (16u<<20)

__device__ __forceinline__ float readlane_f(float v, int l) {
    return __uint_as_float(__builtin_amdgcn_readlane(__float_as_uint(v), l));
}

// ---------------- geometry ----------------
__global__ void geom_kernel(const float* __restrict__ pts, const int* __restrict__ tris,
                            float* __restrict__ geo, float4* __restrict__ bq) {
    int t = blockIdx.x * blockDim.x + threadIdx.x;
    if (t >= T_TRI) return;
    int i0 = tris[3*t], i1 = tris[3*t+1], i2 = tris[3*t+2];
    float ax = pts[3*i0], ay = pts[3*i0+1], az = pts[3*i0+2];
    float bx = pts[3*i1], by = pts[3*i1+1], bz = pts[3*i1+2];
    float cx = pts[3*i2], cy = pts[3*i2+1], cz = pts[3*i2+2];
    float e0x = ax-bx, e0y = ay-by, e0z = az-bz;   // e_ij
    float e1x = ax-cx, e1y = ay-cy, e1z = az-cz;   // e_ik
    float e2x = bx-cx, e2y = by-cy, e2z = bz-cz;   // e_jk
    float mnx = fminf(fminf(e0x,e1x),e2x), mny = fminf(fminf(e0y,e1y),e2y), mnz = fminf(fminf(e0z,e1z),e2z);
    float mxx = fmaxf(fmaxf(e0x,e1x),e2x), mxy = fmaxf(fmaxf(e0y,e1y),e2y), mxz = fmaxf(fmaxf(e0z,e1z),e2z);
    float gx = (ax+bx+cx)*(1.0f/3.0f), gy = (ay+by+cy)*(1.0f/3.0f), gz = (az+bz+cz)*(1.0f/3.0f);
    float sq = (gx*gx + gy*gy) + gz*gz;
    float* g = geo + (size_t)t*12;
    g[0]=mnx; g[1]=mny; g[2]=mnz; g[3]=mxx; g[4]=mxy; g[5]=mxz;
    g[6]=gx;  g[7]=gy;  g[8]=gz;  g[9]=0.f; g[10]=0.f; g[11]=0.f;
    bq[t] = make_float4(gx, gy, gz, sq);
}

// ---------------- knn: R8-measured best config (2 rows/wave, grid 2500) ----------------
// Empirical config ladder: 4rows/1250blk=288us, 2rows/2500blk=278us (BEST),
// 1row/5000blk=300us (R9: ds_read amortization loss beat the occupancy gain).
// This is the R8 kernel verbatim. Candidate enumeration order, distance
// arithmetic (R1/R3/R4-proven order), and event-drain logic unchanged.
#define KTILE 1024
__global__ __launch_bounds__(256) void knn_kernel(const float4* __restrict__ bq, int* __restrict__ nbr) {
    __shared__ float4 tile[KTILE];
    int wave = threadIdx.x >> 6;
    int lane = threadIdx.x & 63;
    int row0 = blockIdx.x * 8 + wave * 2;

    float4 q0 = bq[row0+0], q1 = bq[row0+1];

    float rd0 = INFINITY, rd1 = INFINITY;
    int   ri0 = 0x7FF00000 | lane, ri1 = ri0;     // distinct sentinels
    float th0 = INFINITY, th1 = INFINITY;
    int   mi0 = 0x7FFFFFFF, mi1 = 0x7FFFFFFF;

#define PROC_ROW(R)                                                                  \
    {                                                                                \
        float dot = fmaf(q##R.z, c.z, fmaf(q##R.y, c.y, q##R.x*c.x));                \
        float d = (q##R.w + c.w) - 2.0f*dot;                                         \
        unsigned long long bal = __ballot(d <= th##R);                               \
        while (bal) {                                                                \
            int src = __ffsll(bal) - 1;                                              \
            bal &= bal - 1;                                                          \
            float dc = readlane_f(d, src);                                           \
            int   jc = kbase + src;                                                  \
            if ((dc < th##R) || (dc == th##R && jc < mi##R)) {                       \
                bool less = (rd##R < dc) || (rd##R == dc && ri##R < jc);             \
                int pos = __popcll(__ballot(less) & 0x1FFFFFull);                    \
                float sd = __shfl_up(rd##R, 1);                                      \
                int   si = __shfl_up(ri##R, 1);                                      \
                if (lane < 21) {                                                     \
                    if (lane == pos)      { rd##R = dc; ri##R = jc; }                \
                    else if (lane > pos)  { rd##R = sd; ri##R = si; }                \
                }                                                                    \
                th##R = readlane_f(rd##R, 20);                                       \
                mi##R = __builtin_amdgcn_readlane(ri##R, 20);                        \
            }                                                                        \
        }                                                                            \
    }

    for (int base = 0; base < T_TRI; base += KTILE) {
        int n = min(KTILE, T_TRI - base);
        __syncthreads();
        for (int k = threadIdx.x; k < n; k += 256) tile[k] = bq[base + k];
        for (int k = n + threadIdx.x; k < KTILE; k += 256)
            tile[k] = make_float4(INFINITY, INFINITY, INFINITY, INFINITY);
        __syncthreads();
#pragma unroll 1
        for (int it = 0; it < KTILE/64; ++it) {
            int kbase = base + it*64;
            float4 c = tile[it*64 + lane];
            PROC_ROW(0)
            PROC_ROW(1)
        }
    }
#undef PROC_ROW
    // lane l holds rank-l entry; rank 0 = self, dropped (== reference idx[:,1:])
    if (lane >= 1 && lane < 21) {
        nbr[(row0+0)*KNN_K + lane - 1] = ri0;
        nbr[(row0+1)*KNN_K + lane - 1] = ri1;
    }
}

// ---------------- layer-0 helpers: y0[t][f] = p[t] * rowsum(W1b)[f] ----------------
__global__ void rowsum_kernel(const float* __restrict__ W1, float* __restrict__ rs) {
    int f = threadIdx.x;
    float s = 0.f;
    for (int c = 0; c < H; ++c) s += W1[f*137 + 9 + c];
    rs[f] = s;
}
__global__ void y0_kernel(const float* __restrict__ p, const float* __restrict__ rs, float* __restrict__ Y) {
    int tid = blockIdx.x * blockDim.x + threadIdx.x;   // over T*H
    int t = tid >> 7, f = tid & 127;
    Y[tid] = p[t] * rs[f];
}

// ---------------- weight pre-transpose (once, tiny) ----------------
// WTg[m][c4][f][k] = W_m[f][col0 + 4*c4 + k]  (m*16384 + c4*512 + f*4 + k)
__global__ void wtrans_kernel(const float* __restrict__ W11, const float* __restrict__ W12,
                              const float* __restrict__ W20, const float* __restrict__ W21,
                              const float* __restrict__ W22, float* __restrict__ WTg) {
    int f = threadIdx.x, c = blockIdx.x, m = blockIdx.y;
    const float* W; int stride, col0;
    if      (m == 0) { W = W11; stride = 137; col0 = 9; }
    else if (m == 1) { W = W12; stride = 137; col0 = 9; }
    else if (m == 2) { W = W20; stride = 128; col0 = 0; }
    else if (m == 3) { W = W21; stride = 128; col0 = 0; }
    else             { W = W22; stride = 128; col0 = 0; }
    WTg[m*16384 + (c>>2)*512 + f*4 + (c&3)] = W[f*stride + col0 + c];
}

// ---------------- standalone dense (the W1b mid-layer GEMM): Y = X@W1b^T ----------------
#define DTPB 16
__global__ __launch_bounds__(128) void dense_kernel(const float* __restrict__ A, const float* __restrict__ WTg,
                             float* __restrict__ C) {
    __shared__ float Ar[8][128];
    int f = threadIdx.x;
    int t0 = blockIdx.x * DTPB;
    for (int tt = 0; tt < DTPB; tt += 8) {
        __syncthreads();
#pragma unroll
        for (int j = 0; j < 8; ++j) Ar[j][f] = A[(size_t)(t0+tt+j)*H + f];
        __syncthreads();
        float a0 = 0.f, a1 = 0.f, a2 = 0.f, a3 = 0.f;
        float a4_ = 0.f, a5 = 0.f, a6 = 0.f, a7 = 0.f;
#pragma unroll
        for (int c4 = 0; c4 < 32; ++c4) {
            float4 w = *(const float4*)&WTg[c4*512 + f*4];
#define DROW(J, ACC)                                                        \
            {                                                               \
                float4 v = ((const float4*)Ar[J])[c4];                      \
                ACC = fmaf(w.x, v.x, ACC); ACC = fmaf(w.y, v.y, ACC);       \
                ACC = fmaf(w.z, v.z, ACC); ACC = fmaf(w.w, v.w, ACC);       \
            }
            DROW(0, a0) DROW(1, a1) DROW(2, a2) DROW(3, a3)
            DROW(4, a4_) DROW(5, a5) DROW(6, a6) DROW(7, a7)
#undef DROW
        }
        C[(size_t)(t0+tt+0)*H + f] = a0;
        C[(size_t)(t0+tt+1)*H + f] = a1;
        C[(size_t)(t0+tt+2)*H + f] = a2;
        C[(size_t)(t0+tt+3)*H + f] = a3;
        C[(size_t)(t0+tt+4)*H + f] = a4_;
        C[(size_t)(t0+tt+5)*H + f] = a5;
        C[(size_t)(t0+tt+6)*H + f] = a6;
        C[(size_t)(t0+tt+7)*H + f] = a7;
    }
}

// ---------------- fused edge + W2 (+ head): keeps edge's 20000-wave TLP ----------------
// R8 lesson: fusion is safe iff the gather phase keeps its wave count. This
// block is EXACTLY edge_kernel's geometry (4 tri / 4 waves / 5000 blocks);
// S rows go to 2KB LDS instead of global. W2 phase: f=tid&127, half=tid>>7
// owns rows {half*2, half*2+1}; WTg reads coalesced, Srow reads broadcast;
// accumulation order c=0..127 identical to the verified dense_kernel. Last
// layer folds the Wf dot (2-wave butterfly + LDS combine) + sigmoid.
__global__ __launch_bounds__(256) void edgefused_kernel(const float* __restrict__ Y, const float* __restrict__ geo,
                            const int* __restrict__ nbr, const float* __restrict__ W1,
                            const float* __restrict__ b1, const float* __restrict__ WTg,
                            const float* __restrict__ b2, float* __restrict__ X,
                            const float* __restrict__ Wf, const float* __restrict__ bf,
                            float* __restrict__ out, int last) {
    __shared__ float W1aT[9][128];
    __shared__ float Srow[4][128];
    __shared__ float fpart[4][2];
    for (int idx = threadIdx.x; idx < 9*128; idx += 256) {
        int c = idx >> 7, ff = idx & 127;
        W1aT[c][ff] = W1[ff*137 + c];
    }
    __syncthreads();
    int wave = threadIdx.x >> 6, lane = threadIdx.x & 63;
    int t0b = blockIdx.x * 4;
    {
        int t = t0b + wave;
        float wlo[9], whi[9];
#pragma unroll
        for (int c = 0; c < 9; ++c) { wlo[c] = W1aT[c][lane]; whi[c] = W1aT[c][64+lane]; }
        const float4* g4 = (const float4*)geo;
        float4 s0 = g4[t*3+0], s1 = g4[t*3+1], s2 = g4[t*3+2];
        float b1lo = b1[lane],            b1hi = b1[64+lane];
        float ylo  = Y[(size_t)t*H+lane], yhi  = Y[(size_t)t*H+64+lane];
        float accLo = 0.f, accHi = 0.f;
#pragma unroll
        for (int e = 0; e < KNN_K; ++e) {
            int tg = nbr[t*KNN_K + e];
            float4 t0 = g4[tg*3+0], t1 = g4[tg*3+1], t2 = g4[tg*3+2];
            float r0 = s0.x-t0.x, r1 = s0.y-t0.y, r2 = s0.z-t0.z, r3 = s0.w-t0.w;
            float r4 = s1.x-t1.x, r5 = s1.y-t1.y, r6 = s1.z-t1.z, r7 = s1.w-t1.w;
            float r8 = s2.x-t2.x;
            float gLo = b1lo;
            gLo = fmaf(wlo[0], r0, gLo); gLo = fmaf(wlo[1], r1, gLo); gLo = fmaf(wlo[2], r2, gLo);
            gLo = fmaf(wlo[3], r3, gLo); gLo = fmaf(wlo[4], r4, gLo);
            gLo = fmaf(wlo[5], r5, gLo); gLo = fmaf(wlo[6], r6, gLo);
            gLo = fmaf(wlo[7], r7, gLo); gLo = fmaf(wlo[8], r8, gLo);
            float gHi = b1hi;
            gHi = fmaf(whi[0], r0, gHi); gHi = fmaf(whi[1], r1, gHi); gHi = fmaf(whi[2], r2, gHi);
            gHi = fmaf(whi[3], r3, gHi); gHi = fmaf(whi[4], r4, gHi);
            gHi = fmaf(whi[5], r5, gHi); gHi = fmaf(whi[6], r6, gHi);
            gHi = fmaf(whi[7], r7, gHi); gHi = fmaf(whi[8], r8, gHi);
            accLo += fmaxf(gLo + ylo - Y[(size_t)tg*H + lane], 0.f);
            accHi += fmaxf(gHi + yhi - Y[(size_t)tg*H + 64 + lane], 0.f);
        }
        Srow[wave][lane]    = accLo;
        Srow[wave][64+lane] = accHi;
    }
    __syncthreads();
    // ---- W2 phase ----
    int f = threadIdx.x & 127, half = threadIdx.x >> 7;
    float base = b2[f] * (float)KNN_K;
    float a0 = base, a1 = base;
    const int r0_ = half * 2;
#pragma unroll
    for (int c4 = 0; c4 < 32; ++c4) {
        float4 w = *(const float4*)&WTg[c4*512 + f*4];
        float4 v0 = ((const float4*)Srow[r0_+0])[c4];
        float4 v1 = ((const float4*)Srow[r0_+1])[c4];
        a0 = fmaf(w.x, v0.x, a0); a0 = fmaf(w.y, v0.y, a0);
        a0 = fmaf(w.z, v0.z, a0); a0 = fmaf(w.w, v0.w, a0);
        a1 = fmaf(w.x, v1.x, a1); a1 = fmaf(w.y, v1.y, a1);
        a1 = fmaf(w.z, v1.z, a1); a1 = fmaf(w.w, v1.w, a1);
    }
    if (!last) {
        X[(size_t)(t0b+r0_+0)*H + f] = a0;
        X[(size_t)(t0b+r0_+1)*H + f] = a1;
    } else {
        float wf = Wf[f];
        float p0 = a0*wf, p1 = a1*wf;
#pragma unroll
        for (int off = 32; off >= 1; off >>= 1) {
            p0 += __shfl_xor(p0, off);
            p1 += __shfl_xor(p1, off);
        }
        if (lane == 0) { fpart[wave][0] = p0; fpart[wave][1] = p1; }
        __syncthreads();
        if (threadIdx.x < 4) {
            int r = threadIdx.x;                       // row r in block: waves {2*(r>>1), +1} hold halves
            int h = r >> 1, j = r & 1;
            float z = fpart[2*h][j] + fpart[2*h+1][j] + bf[0];
            out[t0b + h*2 + j] = 1.0f / (1.0f + expf(-z));
        }
    }
}

extern "C" void kernel_launch(void* const* d_in, const int* in_sizes, int n_in,
                              void* d_out, int out_size, void* d_ws, size_t ws_size,
                              hipStream_t stream) {
    (void)in_sizes; (void)n_in; (void)out_size; (void)ws_size;
    const float* pts   = (const float*)d_in[0];
    const int*   tris  = (const int*)d_in[1];
    const float* probs = (const float*)d_in[2];
    const float* W1[3] = {(const float*)d_in[3],  (const float*)d_in[7],  (const float*)d_in[11]};
    const float* b1[3] = {(const float*)d_in[4],  (const float*)d_in[8],  (const float*)d_in[12]};
    const float* W2[3] = {(const float*)d_in[5],  (const float*)d_in[9],  (const float*)d_in[13]};
    const float* b2[3] = {(const float*)d_in[6],  (const float*)d_in[10], (const float*)d_in[14]};
    const float* Wf = (const float*)d_in[15];
    const float* bf = (const float*)d_in[16];
    float* out = (float*)d_out;

    char* ws = (char*)d_ws;
    float*  geo = (float*)(ws + WS_GEO);
    float4* bq  = (float4*)(ws + WS_BQ);
    int*    nbr = (int*)(ws + WS_NBR);
    float*  rs  = (float*)(ws + WS_RS);
    float*  WTg = (float*)(ws + WS_WT);
    float*  X   = (float*)(ws + WS_X);
    float*  Y   = (float*)(ws + WS_Y);

    geom_kernel<<<(T_TRI+255)/256, 256, 0, stream>>>(pts, tris, geo, bq);
    knn_kernel<<<T_TRI/8, 256, 0, stream>>>(bq, nbr);
    rowsum_kernel<<<1, 128, 0, stream>>>(W1[0], rs);
    wtrans_kernel<<<dim3(128,5), 128, 0, stream>>>(W1[1], W1[2], W2[0], W2[1], W2[2], WTg);
    y0_kernel<<<(T_TRI*H)/256, 256, 0, stream>>>(probs, rs, Y);
    for (int l = 0; l < 3; ++l) {
        if (l > 0)
            dense_kernel<<<T_TRI/DTPB, 128, 0, stream>>>(X, WTg + (size_t)(l-1)*16384, Y);
        edgefused_kernel<<<T_TRI/4, 256, 0, stream>>>(Y, geo, nbr, W1[l], b1[l],
                                                      WTg + (size_t)(2+l)*16384, b2[l], X,
                                                      Wf, bf, out, (l == 2) ? 1 : 0);
    }
}

// Round 11
// 522.654 us; speedup vs baseline: 1.3477x; 1.0407x over previous
//
#include <hip/hip_runtime.h>
#include <math.h>

#define T_TRI 20000
#define KNN_K 20
#define H     128

// ---------------- workspace layout (bytes) ----------------
#define WS_GEO   0
#define WS_BQ    (1u<<20)
#define WS_NBR   (2u<<20)
#define WS_RS    (4u<<20)              // rs: 512B
#define WS_WT    ((4u<<20)+4096)       // 5 transposed weights, 320KB
#define WS_MM    (5u<<20)              // minmax: 6 u32
#define WS_CSTART ((5u<<20)+64)        // 4097 u32
#define WS_CPTR  ((5u<<20)+(32u<<10))  // 4096 u32
#define WS_HIST  ((5u<<20)+(64u<<10))  // 4096 u32
#define WS_CID   ((5u<<20)+(128u<<10)) // 20000 i32
#define WS_CSORT ((5u<<20)+(256u<<10)) // 20000 i32
#define WS_OID   ((5u<<20)+(384u<<10)) // 20000 i32
#define WS_BQS   ((5u<<20)+(512u<<10)) // 20000 float4
#define WS_X     (6u<<20)
#define WS_Y     (17u<<20)

__device__ __forceinline__ float readlane_f(float v, int l) {
    return __uint_as_float(__builtin_amdgcn_readlane(__float_as_uint(v), l));
}
// order-preserving float<->uint (for atomicMin/Max on floats)
__device__ __forceinline__ unsigned encf(float f) {
    unsigned u = __float_as_uint(f);
    return (u & 0x80000000u) ? ~u : (u | 0x80000000u);
}
__device__ __forceinline__ float decf(unsigned e) {
    unsigned u = (e & 0x80000000u) ? (e & 0x7FFFFFFFu) : ~e;
    return __uint_as_float(u);
}

// ---------------- init: zero histogram, minmax sentinels ----------------
__global__ void grid_init_kernel(unsigned* __restrict__ hist, unsigned* __restrict__ mm) {
    int i = blockIdx.x * 256 + threadIdx.x;
    if (i < 4096) hist[i] = 0u;
    if (i < 3) mm[i] = 0xFFFFFFFFu;          // mins (uint-encoded)
    if (i >= 3 && i < 6) mm[i] = 0u;         // maxs
}

// ---------------- geometry (+ bary AABB via wave-reduced atomics) ----------------
__global__ void geom_kernel(const float* __restrict__ pts, const int* __restrict__ tris,
                            float* __restrict__ geo, float4* __restrict__ bq,
                            unsigned* __restrict__ mm) {
    int t = blockIdx.x * blockDim.x + threadIdx.x;
    int lane = threadIdx.x & 63;
    bool act = (t < T_TRI);
    int tt = act ? t : 0;
    int i0 = tris[3*tt], i1 = tris[3*tt+1], i2 = tris[3*tt+2];
    float ax = pts[3*i0], ay = pts[3*i0+1], az = pts[3*i0+2];
    float bx = pts[3*i1], by = pts[3*i1+1], bz = pts[3*i1+2];
    float cx = pts[3*i2], cy = pts[3*i2+1], cz = pts[3*i2+2];
    float e0x = ax-bx, e0y = ay-by, e0z = az-bz;   // e_ij
    float e1x = ax-cx, e1y = ay-cy, e1z = az-cz;   // e_ik
    float e2x = bx-cx, e2y = by-cy, e2z = bz-cz;   // e_jk
    float mnx = fminf(fminf(e0x,e1x),e2x), mny = fminf(fminf(e0y,e1y),e2y), mnz = fminf(fminf(e0z,e1z),e2z);
    float mxx = fmaxf(fmaxf(e0x,e1x),e2x), mxy = fmaxf(fmaxf(e0y,e1y),e2y), mxz = fmaxf(fmaxf(e0z,e1z),e2z);
    float gx = (ax+bx+cx)*(1.0f/3.0f), gy = (ay+by+cy)*(1.0f/3.0f), gz = (az+bz+cz)*(1.0f/3.0f);
    float sq = (gx*gx + gy*gy) + gz*gz;
    if (act) {
        float* g = geo + (size_t)t*12;
        g[0]=mnx; g[1]=mny; g[2]=mnz; g[3]=mxx; g[4]=mxy; g[5]=mxz;
        g[6]=gx;  g[7]=gy;  g[8]=gz;  g[9]=0.f; g[10]=0.f; g[11]=0.f;
        bq[t] = make_float4(gx, gy, gz, sq);
    }
    // wave-reduce AABB, one atomic set per wave
    unsigned n0 = act ? encf(gx) : 0xFFFFFFFFu;
    unsigned n1 = act ? encf(gy) : 0xFFFFFFFFu;
    unsigned n2 = act ? encf(gz) : 0xFFFFFFFFu;
    unsigned x0 = act ? encf(gx) : 0u;
    unsigned x1 = act ? encf(gy) : 0u;
    unsigned x2 = act ? encf(gz) : 0u;
#pragma unroll
    for (int off = 32; off >= 1; off >>= 1) {
        n0 = min(n0, (unsigned)__shfl_xor((int)n0, off));
        n1 = min(n1, (unsigned)__shfl_xor((int)n1, off));
        n2 = min(n2, (unsigned)__shfl_xor((int)n2, off));
        x0 = max(x0, (unsigned)__shfl_xor((int)x0, off));
        x1 = max(x1, (unsigned)__shfl_xor((int)x1, off));
        x2 = max(x2, (unsigned)__shfl_xor((int)x2, off));
    }
    if (lane == 0) {
        atomicMin(&mm[0], n0); atomicMin(&mm[1], n1); atomicMin(&mm[2], n2);
        atomicMax(&mm[3], x0); atomicMax(&mm[4], x1); atomicMax(&mm[5], x2);
    }
}

// ---------------- cell assignment + histogram ----------------
__global__ void cellhist_kernel(const float4* __restrict__ bq, const unsigned* __restrict__ mm,
                                int* __restrict__ cellid, unsigned* __restrict__ hist) {
    int t = blockIdx.x * 256 + threadIdx.x;
    if (t >= T_TRI) return;
    float mnx = decf(mm[0]), mny = decf(mm[1]), mnz = decf(mm[2]);
    float mxx = decf(mm[3]), mxy = decf(mm[4]), mxz = decf(mm[5]);
    float ihx = 16.f / fmaxf(mxx-mnx, 1e-30f);
    float ihy = 16.f / fmaxf(mxy-mny, 1e-30f);
    float ihz = 16.f / fmaxf(mxz-mnz, 1e-30f);
    float4 b = bq[t];
    int ix = min(15, max(0, (int)((b.x-mnx)*ihx)));
    int iy = min(15, max(0, (int)((b.y-mny)*ihy)));
    int iz = min(15, max(0, (int)((b.z-mnz)*ihz)));
    int c = (ix<<8) | (iy<<4) | iz;
    cellid[t] = c;
    atomicAdd(&hist[c], 1u);
}

// ---------------- exclusive prefix over 4096 cells (1 block) ----------------
__global__ __launch_bounds__(1024) void prefix_kernel(const unsigned* __restrict__ hist,
                                                      unsigned* __restrict__ cellstart,
                                                      unsigned* __restrict__ cellptr) {
    __shared__ unsigned sbuf[1024];
    int tid = threadIdx.x;
    uint4 v = ((const uint4*)hist)[tid];
    unsigned mysum = v.x + v.y + v.z + v.w;
    sbuf[tid] = mysum;
    __syncthreads();
    for (int off = 1; off < 1024; off <<= 1) {
        unsigned add = (tid >= off) ? sbuf[tid - off] : 0u;
        __syncthreads();
        sbuf[tid] += add;
        __syncthreads();
    }
    unsigned excl = sbuf[tid] - mysum;
    unsigned p0 = excl, p1 = p0 + v.x, p2 = p1 + v.y, p3 = p2 + v.z;
    cellstart[4*tid+0] = p0; cellstart[4*tid+1] = p1;
    cellstart[4*tid+2] = p2; cellstart[4*tid+3] = p3;
    cellptr[4*tid+0] = p0; cellptr[4*tid+1] = p1;
    cellptr[4*tid+2] = p2; cellptr[4*tid+3] = p3;
    if (tid == 1023) cellstart[4096] = p3 + v.w;
}

// ---------------- scatter into cell-sorted order ----------------
// Intra-cell order is atomic-nondeterministic; the selected top-21 set is
// enumeration-order independent (strict lex order on (d, orig idx)), so the
// OUTPUT is deterministic.
__global__ void scatter_kernel(const float4* __restrict__ bq, const int* __restrict__ cellid,
                               unsigned* __restrict__ cellptr, float4* __restrict__ bqs,
                               int* __restrict__ oid, int* __restrict__ csort) {
    int t = blockIdx.x * 256 + threadIdx.x;
    if (t >= T_TRI) return;
    int c = cellid[t];
    unsigned p = atomicAdd(&cellptr[c], 1u);
    bqs[p] = bq[t];
    oid[p]  = t;
    csort[p] = c;
}

// ---------------- grid KNN: exact top-21 with conservative window pruning ----------------
// One wave per (sorted-order) query. Expanding Chebyshev window over 16^3
// cells; after window w, all unexamined candidates have true distance
// >= w*h_axis per axis >= w*hmin; stop when th < (w*hmin - 1e-3)^2 — the 1e-3
// slack dwarfs the ~1e-6 fp error of the distance formula and any cell-edge
// rounding, so no candidate with formula-d <= th can be pruned (exact).
// Distance formula, insert/drain logic, and tie-break (original indices) are
// byte-identical to the R4..R10-passing kernels.
__global__ __launch_bounds__(256) void knn_grid_kernel(const float4* __restrict__ bqs,
        const int* __restrict__ oid, const int* __restrict__ csort,
        const unsigned* __restrict__ cellstart, const unsigned* __restrict__ mm,
        int* __restrict__ nbr) {
    int wave = threadIdx.x >> 6, lane = threadIdx.x & 63;
    int r = blockIdx.x * 4 + wave;
    float4 q = bqs[r];
    int myc = csort[r];
    int cx = (myc>>8)&15, cy = (myc>>4)&15, cz = myc&15;
    float hx = (decf(mm[3]) - decf(mm[0])) * (1.f/16.f);
    float hy = (decf(mm[4]) - decf(mm[1])) * (1.f/16.f);
    float hz = (decf(mm[5]) - decf(mm[2])) * (1.f/16.f);
    float hmin = fminf(hx, fminf(hy, hz));

    float rd = INFINITY;
    int   ri = 0x7FF00000 | lane;     // distinct sentinels
    float th = INFINITY;
    int   mi = 0x7FFFFFFF;

    for (int w = 1; w <= 15; ++w) {
        int W = 2*w + 1, W2 = W*W, tot = W*W2;
        for (int b0 = 0; b0 < tot; b0 += 64) {
            int i = b0 + lane;
            bool val = (i < tot);
            int ii = val ? i : 0;
            int dz = ii % W - w, dy = (ii / W) % W - w, dx = ii / W2 - w;
            int cheb = max(abs(dx), max(abs(dy), abs(dz)));
            val = val && ((w == 1) ? (cheb <= 1) : (cheb == w));
            int ex = cx + dx, ey = cy + dy, ez = cz + dz;
            val = val && ex >= 0 && ex < 16 && ey >= 0 && ey < 16 && ez >= 0 && ez < 16;
            int cell = (ex<<8) | (ey<<4) | ez;
            unsigned cs = 0u, ce = 0u;
            if (val) { cs = cellstart[cell]; ce = cellstart[cell+1]; }
            val = val && (cs < ce);
            unsigned long long cm = __ballot(val);
            while (cm) {
                int cl = __ffsll(cm) - 1;
                cm &= cm - 1;
                unsigned s0 = (unsigned)__builtin_amdgcn_readlane((int)cs, cl);
                unsigned e0 = (unsigned)__builtin_amdgcn_readlane((int)ce, cl);
                for (unsigned base = s0; base < e0; base += 64u) {
                    unsigned k = base + (unsigned)lane;
                    bool kv = (k < e0);
                    float4 c4 = kv ? bqs[k] : make_float4(INFINITY, INFINITY, INFINITY, INFINITY);
                    int ov = kv ? oid[k] : 0x7FFFFFFF;
                    float dot = fmaf(q.z, c4.z, fmaf(q.y, c4.y, q.x*c4.x));
                    float d = (q.w + c4.w) - 2.0f*dot;
                    unsigned long long bal = __ballot(kv && (d <= th));
                    while (bal) {
                        int src = __ffsll(bal) - 1;
                        bal &= bal - 1;
                        float dc = readlane_f(d, src);
                        int   jc = __builtin_amdgcn_readlane(ov, src);
                        if ((dc < th) || (dc == th && jc < mi)) {
                            bool less = (rd < dc) || (rd == dc && ri < jc);
                            int pos = __popcll(__ballot(less) & 0x1FFFFFull);
                            float sd = __shfl_up(rd, 1);
                            int   si = __shfl_up(ri, 1);
                            if (lane < 21) {
                                if (lane == pos)      { rd = dc; ri = jc; }
                                else if (lane > pos)  { rd = sd; ri = si; }
                            }
                            th = readlane_f(rd, 20);
                            mi = __builtin_amdgcn_readlane(ri, 20);
                        }
                    }
                }
            }
        }
        bool covered = (cx-w <= 0) && (cx+w >= 15) && (cy-w <= 0) && (cy+w >= 15)
                    && (cz-w <= 0) && (cz+w >= 15);
        if (covered) break;
        float bd = (float)w * hmin - 1e-3f;
        if (bd > 0.f && th < bd*bd) break;
    }
    // lane l holds rank-l entry (orig indices); rank 0 = self, dropped
    if (lane >= 1 && lane < 21) nbr[oid[r]*KNN_K + lane - 1] = ri;
}

// ---------------- layer-0 helpers: y0[t][f] = p[t] * rowsum(W1b)[f] ----------------
__global__ void rowsum_kernel(const float* __restrict__ W1, float* __restrict__ rs) {
    int f = threadIdx.x;
    float s = 0.f;
    for (int c = 0; c < H; ++c) s += W1[f*137 + 9 + c];
    rs[f] = s;
}
__global__ void y0_kernel(const float* __restrict__ p, const float* __restrict__ rs, float* __restrict__ Y) {
    int tid = blockIdx.x * blockDim.x + threadIdx.x;   // over T*H
    int t = tid >> 7, f = tid & 127;
    Y[tid] = p[t] * rs[f];
}

// ---------------- weight pre-transpose (once, tiny) ----------------
__global__ void wtrans_kernel(const float* __restrict__ W11, const float* __restrict__ W12,
                              const float* __restrict__ W20, const float* __restrict__ W21,
                              const float* __restrict__ W22, float* __restrict__ WTg) {
    int f = threadIdx.x, c = blockIdx.x, m = blockIdx.y;
    const float* W; int stride, col0;
    if      (m == 0) { W = W11; stride = 137; col0 = 9; }
    else if (m == 1) { W = W12; stride = 137; col0 = 9; }
    else if (m == 2) { W = W20; stride = 128; col0 = 0; }
    else if (m == 3) { W = W21; stride = 128; col0 = 0; }
    else             { W = W22; stride = 128; col0 = 0; }
    WTg[m*16384 + (c>>2)*512 + f*4 + (c&3)] = W[f*stride + col0 + c];
}

// ---------------- standalone dense (the W1b mid-layer GEMM): Y = X@W1b^T ----------------
#define DTPB 16
__global__ __launch_bounds__(128) void dense_kernel(const float* __restrict__ A, const float* __restrict__ WTg,
                             float* __restrict__ C) {
    __shared__ float Ar[8][128];
    int f = threadIdx.x;
    int t0 = blockIdx.x * DTPB;
    for (int tt = 0; tt < DTPB; tt += 8) {
        __syncthreads();
#pragma unroll
        for (int j = 0; j < 8; ++j) Ar[j][f] = A[(size_t)(t0+tt+j)*H + f];
        __syncthreads();
        float a0 = 0.f, a1 = 0.f, a2 = 0.f, a3 = 0.f;
        float a4_ = 0.f, a5 = 0.f, a6 = 0.f, a7 = 0.f;
#pragma unroll
        for (int c4 = 0; c4 < 32; ++c4) {
            float4 w = *(const float4*)&WTg[c4*512 + f*4];
#define DROW(J, ACC)                                                        \
            {                                                               \
                float4 v = ((const float4*)Ar[J])[c4];                      \
                ACC = fmaf(w.x, v.x, ACC); ACC = fmaf(w.y, v.y, ACC);       \
                ACC = fmaf(w.z, v.z, ACC); ACC = fmaf(w.w, v.w, ACC);       \
            }
            DROW(0, a0) DROW(1, a1) DROW(2, a2) DROW(3, a3)
            DROW(4, a4_) DROW(5, a5) DROW(6, a6) DROW(7, a7)
#undef DROW
        }
        C[(size_t)(t0+tt+0)*H + f] = a0;
        C[(size_t)(t0+tt+1)*H + f] = a1;
        C[(size_t)(t0+tt+2)*H + f] = a2;
        C[(size_t)(t0+tt+3)*H + f] = a3;
        C[(size_t)(t0+tt+4)*H + f] = a4_;
        C[(size_t)(t0+tt+5)*H + f] = a5;
        C[(size_t)(t0+tt+6)*H + f] = a6;
        C[(size_t)(t0+tt+7)*H + f] = a7;
    }
}

// ---------------- fused edge + W2 (+ head) — unchanged from R10 (passing) ----------------
__global__ __launch_bounds__(256) void edgefused_kernel(const float* __restrict__ Y, const float* __restrict__ geo,
                            const int* __restrict__ nbr, const float* __restrict__ W1,
                            const float* __restrict__ b1, const float* __restrict__ WTg,
                            const float* __restrict__ b2, float* __restrict__ X,
                            const float* __restrict__ Wf, const float* __restrict__ bf,
                            float* __restrict__ out, int last) {
    __shared__ float W1aT[9][128];
    __shared__ float Srow[4][128];
    __shared__ float fpart[4][2];
    for (int idx = threadIdx.x; idx < 9*128; idx += 256) {
        int c = idx >> 7, ff = idx & 127;
        W1aT[c][ff] = W1[ff*137 + c];
    }
    __syncthreads();
    int wave = threadIdx.x >> 6, lane = threadIdx.x & 63;
    int t0b = blockIdx.x * 4;
    {
        int t = t0b + wave;
        float wlo[9], whi[9];
#pragma unroll
        for (int c = 0; c < 9; ++c) { wlo[c] = W1aT[c][lane]; whi[c] = W1aT[c][64+lane]; }
        const float4* g4 = (const float4*)geo;
        float4 s0 = g4[t*3+0], s1 = g4[t*3+1], s2 = g4[t*3+2];
        float b1lo = b1[lane],            b1hi = b1[64+lane];
        float ylo  = Y[(size_t)t*H+lane], yhi  = Y[(size_t)t*H+64+lane];
        float accLo = 0.f, accHi = 0.f;
#pragma unroll
        for (int e = 0; e < KNN_K; ++e) {
            int tg = nbr[t*KNN_K + e];
            float4 t0 = g4[tg*3+0], t1 = g4[tg*3+1], t2 = g4[tg*3+2];
            float r0 = s0.x-t0.x, r1 = s0.y-t0.y, r2 = s0.z-t0.z, r3 = s0.w-t0.w;
            float r4 = s1.x-t1.x, r5 = s1.y-t1.y, r6 = s1.z-t1.z, r7 = s1.w-t1.w;
            float r8 = s2.x-t2.x;
            float gLo = b1lo;
            gLo = fmaf(wlo[0], r0, gLo); gLo = fmaf(wlo[1], r1, gLo); gLo = fmaf(wlo[2], r2, gLo);
            gLo = fmaf(wlo[3], r3, gLo); gLo = fmaf(wlo[4], r4, gLo);
            gLo = fmaf(wlo[5], r5, gLo); gLo = fmaf(wlo[6], r6, gLo);
            gLo = fmaf(wlo[7], r7, gLo); gLo = fmaf(wlo[8], r8, gLo);
            float gHi = b1hi;
            gHi = fmaf(whi[0], r0, gHi); gHi = fmaf(whi[1], r1, gHi); gHi = fmaf(whi[2], r2, gHi);
            gHi = fmaf(whi[3], r3, gHi); gHi = fmaf(whi[4], r4, gHi);
            gHi = fmaf(whi[5], r5, gHi); gHi = fmaf(whi[6], r6, gHi);
            gHi = fmaf(whi[7], r7, gHi); gHi = fmaf(whi[8], r8, gHi);
            accLo += fmaxf(gLo + ylo - Y[(size_t)tg*H + lane], 0.f);
            accHi += fmaxf(gHi + yhi - Y[(size_t)tg*H + 64 + lane], 0.f);
        }
        Srow[wave][lane]    = accLo;
        Srow[wave][64+lane] = accHi;
    }
    __syncthreads();
    int f = threadIdx.x & 127, half = threadIdx.x >> 7;
    float base = b2[f] * (float)KNN_K;
    float a0 = base, a1 = base;
    const int r0_ = half * 2;
#pragma unroll
    for (int c4 = 0; c4 < 32; ++c4) {
        float4 w = *(const float4*)&WTg[c4*512 + f*4];
        float4 v0 = ((const float4*)Srow[r0_+0])[c4];
        float4 v1 = ((const float4*)Srow[r0_+1])[c4];
        a0 = fmaf(w.x, v0.x, a0); a0 = fmaf(w.y, v0.y, a0);
        a0 = fmaf(w.z, v0.z, a0); a0 = fmaf(w.w, v0.w, a0);
        a1 = fmaf(w.x, v1.x, a1); a1 = fmaf(w.y, v1.y, a1);
        a1 = fmaf(w.z, v1.z, a1); a1 = fmaf(w.w, v1.w, a1);
    }
    if (!last) {
        X[(size_t)(t0b+r0_+0)*H + f] = a0;
        X[(size_t)(t0b+r0_+1)*H + f] = a1;
    } else {
        float wf = Wf[f];
        float p0 = a0*wf, p1 = a1*wf;
#pragma unroll
        for (int off = 32; off >= 1; off >>= 1) {
            p0 += __shfl_xor(p0, off);
            p1 += __shfl_xor(p1, off);
        }
        if (lane == 0) { fpart[wave][0] = p0; fpart[wave][1] = p1; }
        __syncthreads();
        if (threadIdx.x < 4) {
            int rr = threadIdx.x;
            int h = rr >> 1, j = rr & 1;
            float z = fpart[2*h][j] + fpart[2*h+1][j] + bf[0];
            out[t0b + h*2 + j] = 1.0f / (1.0f + expf(-z));
        }
    }
}

extern "C" void kernel_launch(void* const* d_in, const int* in_sizes, int n_in,
                              void* d_out, int out_size, void* d_ws, size_t ws_size,
                              hipStream_t stream) {
    (void)in_sizes; (void)n_in; (void)out_size; (void)ws_size;
    const float* pts   = (const float*)d_in[0];
    const int*   tris  = (const int*)d_in[1];
    const float* probs = (const float*)d_in[2];
    const float* W1[3] = {(const float*)d_in[3],  (const float*)d_in[7],  (const float*)d_in[11]};
    const float* b1[3] = {(const float*)d_in[4],  (const float*)d_in[8],  (const float*)d_in[12]};
    const float* W2[3] = {(const float*)d_in[5],  (const float*)d_in[9],  (const float*)d_in[13]};
    const float* b2[3] = {(const float*)d_in[6],  (const float*)d_in[10], (const float*)d_in[14]};
    const float* Wf = (const float*)d_in[15];
    const float* bf = (const float*)d_in[16];
    float* out = (float*)d_out;

    char* ws = (char*)d_ws;
    float*    geo  = (float*)(ws + WS_GEO);
    float4*   bq   = (float4*)(ws + WS_BQ);
    int*      nbr  = (int*)(ws + WS_NBR);
    float*    rs   = (float*)(ws + WS_RS);
    float*    WTg  = (float*)(ws + WS_WT);
    unsigned* mm   = (unsigned*)(ws + WS_MM);
    unsigned* cst  = (unsigned*)(ws + WS_CSTART);
    unsigned* cptr = (unsigned*)(ws + WS_CPTR);
    unsigned* hist = (unsigned*)(ws + WS_HIST);
    int*      cid  = (int*)(ws + WS_CID);
    int*      cso  = (int*)(ws + WS_CSORT);
    int*      oid  = (int*)(ws + WS_OID);
    float4*   bqs  = (float4*)(ws + WS_BQS);
    float*    X    = (float*)(ws + WS_X);
    float*    Y    = (float*)(ws + WS_Y);

    grid_init_kernel<<<16, 256, 0, stream>>>(hist, mm);
    geom_kernel<<<(T_TRI+255)/256, 256, 0, stream>>>(pts, tris, geo, bq, mm);
    cellhist_kernel<<<(T_TRI+255)/256, 256, 0, stream>>>(bq, mm, cid, hist);
    prefix_kernel<<<1, 1024, 0, stream>>>(hist, cst, cptr);
    scatter_kernel<<<(T_TRI+255)/256, 256, 0, stream>>>(bq, cid, cptr, bqs, oid, cso);
    knn_grid_kernel<<<T_TRI/4, 256, 0, stream>>>(bqs, oid, cso, cst, mm, nbr);
    rowsum_kernel<<<1, 128, 0, stream>>>(W1[0], rs);
    wtrans_kernel<<<dim3(128,5), 128, 0, stream>>>(W1[1], W1[2], W2[0], W2[1], W2[2], WTg);
    y0_kernel<<<(T_TRI*H)/256, 256, 0, stream>>>(probs, rs, Y);
    for (int l = 0; l < 3; ++l) {
        if (l > 0)
            dense_kernel<<<T_TRI/DTPB, 128, 0, stream>>>(X, WTg + (size_t)(l-1)*16384, Y);
        edgefused_kernel<<<T_TRI/4, 256, 0, stream>>>(Y, geo, nbr, W1[l], b1[l],
                                                      WTg + (size_t)(2+l)*16384, b2[l], X,
                                                      Wf, bf, out, (l == 2) ? 1 : 0);
    }
}